// Round 1
// baseline (1535.440 us; speedup 1.0000x reference)
//
#include <hip/hip_runtime.h>
#include <math.h>

// Problem constants
#define NB 4
#define CC 768
#define WW 2048
#define HH 12
#define DD 64
#define GG 4
#define CG 192   // C/G
#define HPG 3    // heads per group = (C/G)/D

// ---------------------------------------------------------------------------
// Kernel 1: fused grouped 1x1 conv producing Q,K,V.
// Q/K/V are written to workspace in [N, H, W, D] layout (row = one position's
// head vector, contiguous in D) so the attention kernel gets fully
// vectorizable loads. Writes are strided (stride D) but L2 combines them.
// grid: (W/64, G, N), block 256.
// ---------------------------------------------------------------------------
#define XST 196  // padded LDS stride for x tile: 196*4B = 784B = 49*16B (b128-aligned), 196%32=4 -> conflict-light

__global__ __launch_bounds__(256) void qkv_proj(
    const float* __restrict__ x,    // [N,C,W]
    const float* __restrict__ wq, const float* __restrict__ bq,
    const float* __restrict__ wk, const float* __restrict__ bk,
    const float* __restrict__ wv, const float* __restrict__ bv,
    float* __restrict__ Qg, float* __restrict__ Kg, float* __restrict__ Vg)
{
    __shared__ float xs[64 * XST];   // [wp][c] transposed tile, 50 KB

    const int w0  = blockIdx.x * 64;
    const int g   = blockIdx.y;
    const int n   = blockIdx.z;
    const int tid = threadIdx.x;

    // stage x tile [192 c][64 w] -> xs[wp][c]
    const float* xbase = x + ((size_t)n * CC + (size_t)g * CG) * WW + w0;
    for (int t = tid; t < CG * 64; t += 256) {
        int c = t >> 6, wp = t & 63;                 // lanes walk wp -> coalesced global
        xs[wp * XST + c] = xbase[(size_t)c * WW + wp];
    }
    __syncthreads();

    const int o_l = tid >> 6;   // 0..3 (wave id)
    const int wp  = tid & 63;

    for (int oo = 0; oo < CG / 4; ++oo) {
        const int o  = oo * 4 + o_l;
        const int co = g * CG + o;                   // output channel
        const float4* wq4 = (const float4*)(wq + ((size_t)g * CG + o) * CG);
        const float4* wk4 = (const float4*)(wk + ((size_t)g * CG + o) * CG);
        const float4* wv4 = (const float4*)(wv + ((size_t)g * CG + o) * CG);

        float aq = 0.f, ak = 0.f, av = 0.f;
        #pragma unroll 8
        for (int c4 = 0; c4 < CG / 4; ++c4) {
            float4 xv = *(const float4*)&xs[wp * XST + c4 * 4];
            float4 a = wq4[c4], b = wk4[c4], c = wv4[c4];
            aq += a.x * xv.x + a.y * xv.y + a.z * xv.z + a.w * xv.w;
            ak += b.x * xv.x + b.y * xv.y + b.z * xv.z + b.w * xv.w;
            av += c.x * xv.x + c.y * xv.y + c.z * xv.z + c.w * xv.w;
        }
        aq += bq[co]; ak += bk[co]; av += bv[co];

        const int h = g * HPG + (o >> 6);
        const int d = o & 63;
        const size_t oidx = (((size_t)n * HH + h) * WW + (w0 + wp)) * DD + d;
        Qg[oidx] = aq; Kg[oidx] = ak; Vg[oidx] = av;
    }
}

// ---------------------------------------------------------------------------
// Kernel 2: fp32 flash attention.
// One block per (n, h, 64-query tile). 64-wide K tiles, online softmax.
// Thread (ty,tx): ty=tid>>4 (q rows ty*4..+3), tx=tid&15.
//   S block: rows ty*4+ii, cols tx+16*jj (strided cols -> conflict-free LDS)
//   O block: rows ty*4+ii, cols tx*4+dd
// LDS stride 68 (=4 mod 32) makes all hot accesses <=2-way (free).
// grid: (W/64, H, N), block 256.
// ---------------------------------------------------------------------------
#define SS 68

__global__ __launch_bounds__(256) void attn(
    const float* __restrict__ Qg, const float* __restrict__ Kg,
    const float* __restrict__ Vg, const float* __restrict__ mask,
    float* __restrict__ out)
{
    __shared__ float Ks[64 * SS];
    __shared__ float Vs[64 * SS];
    __shared__ float Sm[64 * SS];
    __shared__ float red[64 * 4];
    __shared__ float mrow[64], lrow[64], arow[64], Ms[64];

    const int q0  = blockIdx.x * 64;
    const int h   = blockIdx.y;
    const int n   = blockIdx.z;
    const int tid = threadIdx.x;
    const int tx  = tid & 15, ty = tid >> 4;
    const int r   = tid >> 2, part = tid & 3;   // softmax row mapping

    const size_t nh = (size_t)n * HH + h;
    const float* Qbase = Qg + (nh * WW + q0) * DD;   // [64 q][64 d]
    const float* Kbase = Kg + nh * WW * DD;
    const float* Vbase = Vg + nh * WW * DD;
    const float* mbase = mask + (size_t)n * WW;

    if (tid < 64) { mrow[tid] = -1e30f; lrow[tid] = 0.f; }

    float acc[4][4];
    #pragma unroll
    for (int i = 0; i < 4; ++i)
        #pragma unroll
        for (int j = 0; j < 4; ++j) acc[i][j] = 0.f;

    for (int kt = 0; kt < WW / 64; ++kt) {
        const int k0 = kt * 64;
        // ---- load K/V tiles (coalesced global over d, conflict-free LDS) ----
        for (int t = tid; t < 4096; t += 256) {
            int k = t >> 6, d = t & 63;
            Ks[k * SS + d] = Kbase[(size_t)(k0 + k) * DD + d];
            Vs[k * SS + d] = Vbase[(size_t)(k0 + k) * DD + d];
        }
        if (tid < 64) Ms[tid] = mbase[k0 + tid];
        __syncthreads();

        // ---- S = (Q K^T) * 1/8 + mask ----
        float sa[4][4];
        #pragma unroll
        for (int i = 0; i < 4; ++i)
            #pragma unroll
            for (int j = 0; j < 4; ++j) sa[i][j] = 0.f;

        #pragma unroll 4
        for (int dv = 0; dv < 16; ++dv) {
            float4 qv[4], kv[4];
            #pragma unroll
            for (int ii = 0; ii < 4; ++ii)
                qv[ii] = *(const float4*)(Qbase + (size_t)(ty * 4 + ii) * DD + dv * 4);
            #pragma unroll
            for (int jj = 0; jj < 4; ++jj)
                kv[jj] = *(const float4*)&Ks[(tx + 16 * jj) * SS + dv * 4];
            #pragma unroll
            for (int ii = 0; ii < 4; ++ii)
                #pragma unroll
                for (int jj = 0; jj < 4; ++jj) {
                    sa[ii][jj] += qv[ii].x * kv[jj].x + qv[ii].y * kv[jj].y
                                + qv[ii].z * kv[jj].z + qv[ii].w * kv[jj].w;
                }
        }
        #pragma unroll
        for (int ii = 0; ii < 4; ++ii)
            #pragma unroll
            for (int jj = 0; jj < 4; ++jj) {
                int k = tx + 16 * jj;
                Sm[(ty * 4 + ii) * SS + k] = sa[ii][jj] * 0.125f + Ms[k];
            }
        __syncthreads();

        // ---- softmax R1: partial row max ----
        {
            float lm = -1e30f;
            int base = r * SS + part * 16;
            #pragma unroll
            for (int j = 0; j < 16; ++j) lm = fmaxf(lm, Sm[base + j]);
            red[r * 4 + part] = lm;
        }
        __syncthreads();
        // ---- R2: new running max + rescale factor ----
        if (tid < 64) {
            float mt = fmaxf(fmaxf(red[tid * 4 + 0], red[tid * 4 + 1]),
                             fmaxf(red[tid * 4 + 2], red[tid * 4 + 3]));
            float mo = mrow[tid];
            float mn = fmaxf(mo, mt);
            mrow[tid] = mn;
            arow[tid] = __expf(mo - mn);
        }
        __syncthreads();
        // ---- E: exponentiate in place + partial sums ----
        {
            float mr = mrow[r];
            float ps = 0.f;
            int base = r * SS + part * 16;
            #pragma unroll
            for (int j = 0; j < 16; ++j) {
                float p = __expf(Sm[base + j] - mr);
                Sm[base + j] = p;
                ps += p;
            }
            red[r * 4 + part] = ps;
        }
        __syncthreads();
        if (tid < 64) {
            lrow[tid] = lrow[tid] * arow[tid]
                      + red[tid * 4 + 0] + red[tid * 4 + 1]
                      + red[tid * 4 + 2] + red[tid * 4 + 3];
        }

        // ---- rescale accumulators, then O += P * V ----
        {
            float a0 = arow[ty * 4 + 0], a1 = arow[ty * 4 + 1];
            float a2 = arow[ty * 4 + 2], a3 = arow[ty * 4 + 3];
            #pragma unroll
            for (int j = 0; j < 4; ++j) {
                acc[0][j] *= a0; acc[1][j] *= a1; acc[2][j] *= a2; acc[3][j] *= a3;
            }
        }
        #pragma unroll 8
        for (int k = 0; k < 64; ++k) {
            float4 vv = *(const float4*)&Vs[k * SS + tx * 4];
            float p0 = Sm[(ty * 4 + 0) * SS + k];
            float p1 = Sm[(ty * 4 + 1) * SS + k];
            float p2 = Sm[(ty * 4 + 2) * SS + k];
            float p3 = Sm[(ty * 4 + 3) * SS + k];
            acc[0][0] += p0 * vv.x; acc[0][1] += p0 * vv.y; acc[0][2] += p0 * vv.z; acc[0][3] += p0 * vv.w;
            acc[1][0] += p1 * vv.x; acc[1][1] += p1 * vv.y; acc[1][2] += p1 * vv.z; acc[1][3] += p1 * vv.w;
            acc[2][0] += p2 * vv.x; acc[2][1] += p2 * vv.y; acc[2][2] += p2 * vv.z; acc[2][3] += p2 * vv.w;
            acc[3][0] += p3 * vv.x; acc[3][1] += p3 * vv.y; acc[3][2] += p3 * vv.z; acc[3][3] += p3 * vv.w;
        }
        __syncthreads();
    }

    // ---- epilogue: divide by l, transpose via LDS, coalesced store ----
    {
        float linv[4];
        #pragma unroll
        for (int ii = 0; ii < 4; ++ii) linv[ii] = 1.0f / lrow[ty * 4 + ii];
        #pragma unroll
        for (int ii = 0; ii < 4; ++ii)
            #pragma unroll
            for (int dd = 0; dd < 4; ++dd)
                Sm[(tx * 4 + dd) * SS + ty * 4 + ii] = acc[ii][dd] * linv[ii];
    }
    __syncthreads();
    float* obase = out + ((size_t)n * CC + (size_t)h * DD) * WW + q0;
    for (int t = tid; t < 4096; t += 256) {
        int d = t >> 6, i = t & 63;
        obase[(size_t)d * WW + i] = Sm[d * SS + i];
    }
}

// ---------------------------------------------------------------------------
extern "C" void kernel_launch(void* const* d_in, const int* in_sizes, int n_in,
                              void* d_out, int out_size, void* d_ws, size_t ws_size,
                              hipStream_t stream) {
    const float* x    = (const float*)d_in[0];
    const float* mask = (const float*)d_in[1];
    const float* wq   = (const float*)d_in[2];
    const float* bq   = (const float*)d_in[3];
    const float* wk   = (const float*)d_in[4];
    const float* bk   = (const float*)d_in[5];
    const float* wv   = (const float*)d_in[6];
    const float* bv   = (const float*)d_in[7];
    float* out = (float*)d_out;

    const size_t per = (size_t)NB * HH * WW * DD;   // 6,291,456 floats
    float* Qg = (float*)d_ws;
    float* Kg = Qg + per;
    float* Vg = Kg + per;

    dim3 gp(WW / 64, GG, NB);
    hipLaunchKernelGGL(qkv_proj, gp, dim3(256), 0, stream,
                       x, wq, bq, wk, bk, wv, bv, Qg, Kg, Vg);

    dim3 ga(WW / 64, HH, NB);
    hipLaunchKernelGGL(attn, ga, dim3(256), 0, stream,
                       Qg, Kg, Vg, mask, out);
}

// Round 2
// 944.605 us; speedup vs baseline: 1.6255x; 1.6255x over previous
//
#include <hip/hip_runtime.h>
#include <math.h>

typedef __attribute__((ext_vector_type(4))) float floatx4;
typedef __attribute__((ext_vector_type(8))) short shortx8;   // 8 bf16 (4 VGPRs)

#define NB 4
#define CC 768
#define WW 2048
#define HH 12
#define DD 64
#define GG 4
#define CG 192
#define HPG 3

__device__ __forceinline__ short f2bf(float f) {
    union { float f; unsigned u; } v; v.f = f;
    unsigned r = v.u + 0x7fffu + ((v.u >> 16) & 1u);   // round-to-nearest-even
    return (short)(r >> 16);
}

// DPP row (16-lane) butterfly reductions on the VALU pipe (row_ror:8/4/2/1)
template<int CTRL>
__device__ __forceinline__ float dppror(float v) {
    return __int_as_float(__builtin_amdgcn_update_dpp(
        0, __float_as_int(v), CTRL, 0xf, 0xf, false));
}
__device__ __forceinline__ float rmax16(float v) {
    v = fmaxf(v, dppror<0x128>(v));
    v = fmaxf(v, dppror<0x124>(v));
    v = fmaxf(v, dppror<0x122>(v));
    v = fmaxf(v, dppror<0x121>(v));
    return v;
}
__device__ __forceinline__ float rsum16(float v) {
    v += dppror<0x128>(v);
    v += dppror<0x124>(v);
    v += dppror<0x122>(v);
    v += dppror<0x121>(v);
    return v;
}

// ---------------------------------------------------------------------------
// Kernel 1: grouped 1x1 conv (fp32 compute), emitting bf16 Q,K [N,H,W,D] and
// bf16 V [N,H,D,W]. Weights via wave-uniform (SGPR) addresses -> s_load.
// grid (W/64, G, N), block 256. Wave w computes 16 output rows, lanes = w pos.
// ---------------------------------------------------------------------------
#define QST 72   // short stride: 144B rows -> 16B-aligned b128 LDS ops

__global__ __launch_bounds__(256) void qkv_proj(
    const float* __restrict__ x,
    const float* __restrict__ wq, const float* __restrict__ bq,
    const float* __restrict__ wk, const float* __restrict__ bk,
    const float* __restrict__ wv, const float* __restrict__ bv,
    short* __restrict__ Qb, short* __restrict__ Kb, short* __restrict__ Vb)
{
    __shared__ __align__(16) short qs[64 * QST];
    __shared__ __align__(16) short ks2[64 * QST];

    const int w0  = blockIdx.x * 64;
    const int g   = blockIdx.y;
    const int n   = blockIdx.z;
    const int tid = threadIdx.x;
    const int wid = __builtin_amdgcn_readfirstlane(tid >> 6);  // SGPR wave id
    const int wp  = tid & 63;

    const float* xg = x + ((size_t)n * CC + (size_t)g * CG) * WW + w0 + wp;

    for (int hc = 0; hc < HPG; ++hc) {
        const int h   = g * HPG + hc;
        const int obg = g * CG + hc * 64 + wid * 16;   // global out-channel base (SGPR)
        const size_t nh = (size_t)n * HH + h;

        float aq[16], ak[16], av[16];
        #pragma unroll
        for (int r = 0; r < 16; ++r) {
            aq[r] = bq[obg + r]; ak[r] = bk[obg + r]; av[r] = bv[obg + r];
        }

        for (int ch = 0; ch < 12; ++ch) {          // 12 chunks of 16 channels
            float xr[16];
            #pragma unroll
            for (int c = 0; c < 16; ++c)
                xr[c] = xg[(size_t)(ch * 16 + c) * WW];
            #pragma unroll
            for (int r = 0; r < 16; ++r) {
                const float* wqr = wq + (size_t)(obg + r) * CG + ch * 16;  // uniform -> s_load
                const float* wkr = wk + (size_t)(obg + r) * CG + ch * 16;
                const float* wvr = wv + (size_t)(obg + r) * CG + ch * 16;
                #pragma unroll
                for (int c = 0; c < 16; ++c) {
                    aq[r] += wqr[c] * xr[c];
                    ak[r] += wkr[c] * xr[c];
                    av[r] += wvr[c] * xr[c];
                }
            }
        }

        // V: [N,H,D,W] -> directly coalesced bf16 stores
        #pragma unroll
        for (int r = 0; r < 16; ++r)
            Vb[(nh * DD + wid * 16 + r) * WW + w0 + wp] = f2bf(av[r]);

        // Q/K: restage via LDS for coalesced [N,H,W,D] stores
        shortx8 pq0, pq1, pk0, pk1;
        #pragma unroll
        for (int j = 0; j < 8; ++j) {
            pq0[j] = f2bf(aq[j]); pq1[j] = f2bf(aq[j + 8]);
            pk0[j] = f2bf(ak[j]); pk1[j] = f2bf(ak[j + 8]);
        }
        *(shortx8*)&qs [wp * QST + wid * 16]     = pq0;
        *(shortx8*)&qs [wp * QST + wid * 16 + 8] = pq1;
        *(shortx8*)&ks2[wp * QST + wid * 16]     = pk0;
        *(shortx8*)&ks2[wp * QST + wid * 16 + 8] = pk1;
        __syncthreads();
        #pragma unroll
        for (int t2 = 0; t2 < 2; ++t2) {
            int t = tid + t2 * 256;
            int row = t >> 3, c8 = (t & 7) * 8;
            *(shortx8*)&Qb[(nh * WW + w0 + row) * DD + c8] = *(const shortx8*)&qs [row * QST + c8];
            *(shortx8*)&Kb[(nh * WW + w0 + row) * DD + c8] = *(const shortx8*)&ks2[row * QST + c8];
        }
        __syncthreads();   // qs reused next hc
    }
}

// ---------------------------------------------------------------------------
// Kernel 2: bf16 MFMA flash attention. Block = 4 waves, 64 queries (16/wave).
// All MFMA operand fragments are direct 16B global loads; softmax in-register
// (DPP row reductions); P round-trips via wave-private LDS (no barriers).
// grid (W/64, H, N), block 256.
// ---------------------------------------------------------------------------
#define PST 72   // 144B rows: b128-aligned A-frag reads
#define OST 68

__global__ __launch_bounds__(256) void attn(
    const short* __restrict__ Qb, const short* __restrict__ Kb,
    const short* __restrict__ Vb, const float* __restrict__ mask,
    float* __restrict__ out)
{
    __shared__ __align__(16) short Pl[4 * 16 * PST];   // 9216 B, per-wave strips
    __shared__ __align__(16) float Ol[DD * OST];       // 17408 B, epilogue transpose

    const int q0   = blockIdx.x * 64;
    const int h    = blockIdx.y;
    const int n    = blockIdx.z;
    const int tid  = threadIdx.x;
    const int wid  = __builtin_amdgcn_readfirstlane(tid >> 6);
    const int lane = tid & 63;
    const int l15  = lane & 15;
    const int quad = lane >> 4;

    const size_t nh = (size_t)n * HH + h;
    const short* Kbase = Kb + nh * WW * DD;   // [key][d]
    const short* Vbase = Vb + nh * DD * WW;   // [d][w]
    const float* mbase = mask + (size_t)n * WW;

    // Q fragments: A[m=l15][k=quad*8+j], two 32-wide k-steps
    shortx8 qf[2];
    {
        const short* qp = Qb + (nh * WW + q0 + wid * 16 + l15) * DD + quad * 8;
        qf[0] = *(const shortx8*)(qp);
        qf[1] = *(const shortx8*)(qp + 32);
    }

    floatx4 oacc[4];
    #pragma unroll
    for (int nn2 = 0; nn2 < 4; ++nn2) oacc[nn2] = (floatx4)0.0f;
    float mst[4] = {-1e30f, -1e30f, -1e30f, -1e30f};
    float lst[4] = {0.f, 0.f, 0.f, 0.f};

    short* Pw = Pl + wid * 16 * PST;

    for (int kt = 0; kt < WW / 64; ++kt) {
        const int k0 = kt * 64;

        shortx8 kf[4][2], vf[4][2];
        #pragma unroll
        for (int jj = 0; jj < 4; ++jj) {
            const short* kp = Kbase + (size_t)(k0 + 16 * jj + l15) * DD + quad * 8;
            kf[jj][0] = *(const shortx8*)kp;
            kf[jj][1] = *(const shortx8*)(kp + 32);
        }
        #pragma unroll
        for (int nn2 = 0; nn2 < 4; ++nn2) {
            const short* vp = Vbase + (size_t)(nn2 * 16 + l15) * WW + k0 + quad * 8;
            vf[nn2][0] = *(const shortx8*)vp;
            vf[nn2][1] = *(const shortx8*)(vp + 32);
        }
        float mv[4];
        #pragma unroll
        for (int jj = 0; jj < 4; ++jj) mv[jj] = mbase[k0 + 16 * jj + l15];

        // S = Q K^T  (rows=q via C-layout, cols=key)
        floatx4 sacc[4];
        #pragma unroll
        for (int jj = 0; jj < 4; ++jj) {
            sacc[jj] = (floatx4)0.0f;
            sacc[jj] = __builtin_amdgcn_mfma_f32_16x16x32_bf16(qf[0], kf[jj][0], sacc[jj], 0, 0, 0);
            sacc[jj] = __builtin_amdgcn_mfma_f32_16x16x32_bf16(qf[1], kf[jj][1], sacc[jj], 0, 0, 0);
        }

        float s[4][4];
        #pragma unroll
        for (int jj = 0; jj < 4; ++jj)
            #pragma unroll
            for (int r = 0; r < 4; ++r)
                s[jj][r] = sacc[jj][r] * 0.125f + mv[jj];

        // online softmax, rows = quad*4+r live in one DPP row (16 lanes)
        float alpha[4];
        #pragma unroll
        for (int r = 0; r < 4; ++r) {
            float tm = fmaxf(fmaxf(s[0][r], s[1][r]), fmaxf(s[2][r], s[3][r]));
            tm = rmax16(tm);
            float mn = fmaxf(mst[r], tm);
            alpha[r] = __expf(mst[r] - mn);
            mst[r] = mn;
        }
        #pragma unroll
        for (int r = 0; r < 4; ++r) {
            float ps = 0.f;
            #pragma unroll
            for (int jj = 0; jj < 4; ++jj) {
                float p = __expf(s[jj][r] - mst[r]);
                s[jj][r] = p;
                ps += p;
            }
            ps = rsum16(ps);
            lst[r] = lst[r] * alpha[r] + ps;
        }

        // P -> LDS (bf16), C-layout scatter writes (wave-private strip)
        #pragma unroll
        for (int jj = 0; jj < 4; ++jj)
            #pragma unroll
            for (int r = 0; r < 4; ++r)
                Pw[(quad * 4 + r) * PST + 16 * jj + l15] = f2bf(s[jj][r]);

        #pragma unroll
        for (int nn2 = 0; nn2 < 4; ++nn2)
            #pragma unroll
            for (int r = 0; r < 4; ++r)
                oacc[nn2][r] *= alpha[r];

        // P as A-fragments (b128 reads)
        shortx8 pf0 = *(const shortx8*)&Pw[l15 * PST + quad * 8];
        shortx8 pf1 = *(const shortx8*)&Pw[l15 * PST + 32 + quad * 8];

        // O += P V   (B-frag: V[key][d] from [d][w] layout rows)
        #pragma unroll
        for (int nn2 = 0; nn2 < 4; ++nn2) {
            oacc[nn2] = __builtin_amdgcn_mfma_f32_16x16x32_bf16(pf0, vf[nn2][0], oacc[nn2], 0, 0, 0);
            oacc[nn2] = __builtin_amdgcn_mfma_f32_16x16x32_bf16(pf1, vf[nn2][1], oacc[nn2], 0, 0, 0);
        }
    }

    // epilogue: normalize, transpose via LDS, coalesced [d][w] stores
    float linv[4];
    #pragma unroll
    for (int r = 0; r < 4; ++r) linv[r] = 1.0f / lst[r];
    #pragma unroll
    for (int nn2 = 0; nn2 < 4; ++nn2)
        #pragma unroll
        for (int r = 0; r < 4; ++r)
            Ol[(nn2 * 16 + l15) * OST + wid * 16 + quad * 4 + r] = oacc[nn2][r] * linv[r];
    __syncthreads();
    float* obase = out + (nh * DD) * WW + q0;
    #pragma unroll
    for (int i = 0; i < 4; ++i) {
        int idx = tid * 4 + i * 1024;
        int d = idx >> 6, qq = idx & 63;
        *(floatx4*)&obase[(size_t)d * WW + qq] = *(const floatx4*)&Ol[d * OST + qq];
    }
}

// ---------------------------------------------------------------------------
extern "C" void kernel_launch(void* const* d_in, const int* in_sizes, int n_in,
                              void* d_out, int out_size, void* d_ws, size_t ws_size,
                              hipStream_t stream) {
    const float* x    = (const float*)d_in[0];
    const float* mask = (const float*)d_in[1];
    const float* wq   = (const float*)d_in[2];
    const float* bq   = (const float*)d_in[3];
    const float* wk   = (const float*)d_in[4];
    const float* bk   = (const float*)d_in[5];
    const float* wv   = (const float*)d_in[6];
    const float* bv   = (const float*)d_in[7];
    float* out = (float*)d_out;

    const size_t per = (size_t)NB * HH * WW * DD;   // 6,291,456 bf16 each
    short* Qb = (short*)d_ws;
    short* Kb = Qb + per;
    short* Vb = Kb + per;

    hipLaunchKernelGGL(qkv_proj, dim3(WW / 64, GG, NB), dim3(256), 0, stream,
                       x, wq, bq, wk, bk, wv, bv, Qb, Kb, Vb);
    hipLaunchKernelGGL(attn, dim3(WW / 64, HH, NB), dim3(256), 0, stream,
                       Qb, Kb, Vb, mask, out);
}

// Round 3
// 506.182 us; speedup vs baseline: 3.0334x; 1.8661x over previous
//
#include <hip/hip_runtime.h>
#include <math.h>

typedef __attribute__((ext_vector_type(4))) float floatx4;
typedef __attribute__((ext_vector_type(8))) short shortx8;   // 8 bf16
typedef __attribute__((ext_vector_type(4))) short shortx4;   // 4 bf16 (8B)

#define NB 4
#define CC 768
#define WW 2048
#define HH 12
#define DD 64
#define GG 4
#define CG 192
#define HPG 3
#define SHIFT 8.0f

__device__ __forceinline__ short f2bf(float f) {
    union { float f; unsigned u; } v; v.f = f;
    unsigned r = v.u + 0x7fffu + ((v.u >> 16) & 1u);   // RNE
    return (short)(r >> 16);
}
__device__ __forceinline__ float bf2f(short h) {
    union { unsigned u; float f; } v;
    v.u = ((unsigned)(unsigned short)h) << 16;
    return v.f;
}

// 16-lane (DPP row) sum on the VALU pipe
template<int CTRL>
__device__ __forceinline__ float dppror(float v) {
    return __int_as_float(__builtin_amdgcn_update_dpp(
        0, __float_as_int(v), CTRL, 0xf, 0xf, false));
}
__device__ __forceinline__ float rsum16(float v) {
    v += dppror<0x128>(v);
    v += dppror<0x124>(v);
    v += dppror<0x122>(v);
    v += dppror<0x121>(v);
    return v;
}

// ---------------------------------------------------------------------------
// Prep 1: x [N,C,W] fp32 -> XTh/XTl [N,W,C] bf16 hi/lo (transpose + split).
// grid (W/64, C/64, N), block 256 = (64 w) x (4 c-subtiles of 16).
// ---------------------------------------------------------------------------
__global__ __launch_bounds__(256) void prep_x(
    const float* __restrict__ x, short* __restrict__ XTh, short* __restrict__ XTl)
{
    const int w0 = blockIdx.x * 64;
    const int c0 = blockIdx.y * 64;
    const int n  = blockIdx.z;
    const int tid = threadIdx.x;
    const int w  = tid & 63;
    const int cb = c0 + (tid >> 6) * 16;

    float xv[16];
    #pragma unroll
    for (int j = 0; j < 16; ++j)
        xv[j] = x[((size_t)n * CC + cb + j) * WW + w0 + w];

    shortx8 hi0, hi1, lo0, lo1;
    #pragma unroll
    for (int j = 0; j < 8; ++j) {
        short h0 = f2bf(xv[j]);     hi0[j] = h0; lo0[j] = f2bf(xv[j]     - bf2f(h0));
        short h1 = f2bf(xv[j + 8]); hi1[j] = h1; lo1[j] = f2bf(xv[j + 8] - bf2f(h1));
    }
    const size_t ro = ((size_t)n * WW + w0 + w) * CC + cb;
    *(shortx8*)&XTh[ro]     = hi0;
    *(shortx8*)&XTh[ro + 8] = hi1;
    *(shortx8*)&XTl[ro]     = lo0;
    *(shortx8*)&XTl[ro + 8] = lo1;
}

// ---------------------------------------------------------------------------
// Prep 2: wq/wk/wv [G,CG,CG] fp32 -> Wh/Wl bf16 hi/lo, concat [mat][G,CG,CG].
// ---------------------------------------------------------------------------
#define WSZ (GG * CG * CG)   // 147456

__global__ __launch_bounds__(256) void prep_w(
    const float* __restrict__ wq, const float* __restrict__ wk,
    const float* __restrict__ wv, short* __restrict__ Wh, short* __restrict__ Wl)
{
    const int t = blockIdx.x * 256 + threadIdx.x;
    if (t >= WSZ) return;
    const float* src[3] = {wq, wk, wv};
    #pragma unroll
    for (int m = 0; m < 3; ++m) {
        float v = src[m][t];
        short h = f2bf(v);
        Wh[m * WSZ + t] = h;
        Wl[m * WSZ + t] = f2bf(v - bf2f(h));
    }
}

// ---------------------------------------------------------------------------
// Kernel: grouped 1x1 conv as bf16 hi/lo MFMA GEMM (fp32-accurate).
// Y[192 o][64 p] per block; wave wid owns o in [wid*48, wid*48+48).
// No LDS, no barriers: all fragments are direct 16B global loads.
// Emits Q,K bf16 [N,H,W,D] and V bf16 [N,H,D,W].
// grid (W/64, G, N), block 256.
// ---------------------------------------------------------------------------
__global__ __launch_bounds__(256) void qkv_gemm(
    const short* __restrict__ XTh, const short* __restrict__ XTl,
    const short* __restrict__ Wh, const short* __restrict__ Wl,
    const float* __restrict__ bq, const float* __restrict__ bk,
    const float* __restrict__ bv,
    short* __restrict__ Qb, short* __restrict__ Kb, short* __restrict__ Vb)
{
    const int p0   = blockIdx.x * 64;
    const int g    = blockIdx.y;
    const int n    = blockIdx.z;
    const int tid  = threadIdx.x;
    const int wid  = __builtin_amdgcn_readfirstlane(tid >> 6);
    const int lane = tid & 63;
    const int l15  = lane & 15;
    const int quad = lane >> 4;
    const int ob   = wid * 48;

    const short* xh = XTh + ((size_t)n * WW + p0 + l15) * CC + g * CG + quad * 8;
    const short* xl = XTl + ((size_t)n * WW + p0 + l15) * CC + g * CG + quad * 8;
    const float* biases[3] = {bq, bk, bv};
    short* outs[3] = {Qb, Kb, Vb};

    #pragma unroll
    for (int mat = 0; mat < 3; ++mat) {
        const short* whm = Wh + (size_t)mat * WSZ + ((size_t)g * CG + ob + l15) * CG + quad * 8;
        const short* wlm = Wl + (size_t)mat * WSZ + ((size_t)g * CG + ob + l15) * CG + quad * 8;

        floatx4 acc[3][4];
        #pragma unroll
        for (int mi = 0; mi < 3; ++mi)
            #pragma unroll
            for (int ni = 0; ni < 4; ++ni) acc[mi][ni] = (floatx4)0.0f;

        #pragma unroll
        for (int ks = 0; ks < 6; ++ks) {
            const int k0 = ks * 32;
            shortx8 ah[3], al[3], bh[4], bl[4];
            #pragma unroll
            for (int mi = 0; mi < 3; ++mi) {
                ah[mi] = *(const shortx8*)(whm + (size_t)mi * 16 * CG + k0);
                al[mi] = *(const shortx8*)(wlm + (size_t)mi * 16 * CG + k0);
            }
            #pragma unroll
            for (int ni = 0; ni < 4; ++ni) {
                bh[ni] = *(const shortx8*)(xh + (size_t)ni * 16 * CC + k0);
                bl[ni] = *(const shortx8*)(xl + (size_t)ni * 16 * CC + k0);
            }
            #pragma unroll
            for (int mi = 0; mi < 3; ++mi)
                #pragma unroll
                for (int ni = 0; ni < 4; ++ni) {
                    acc[mi][ni] = __builtin_amdgcn_mfma_f32_16x16x32_bf16(ah[mi], bh[ni], acc[mi][ni], 0, 0, 0);
                    acc[mi][ni] = __builtin_amdgcn_mfma_f32_16x16x32_bf16(ah[mi], bl[ni], acc[mi][ni], 0, 0, 0);
                    acc[mi][ni] = __builtin_amdgcn_mfma_f32_16x16x32_bf16(al[mi], bh[ni], acc[mi][ni], 0, 0, 0);
                }
        }

        const float* bias = biases[mat];
        short* Y = outs[mat];
        #pragma unroll
        for (int mi = 0; mi < 3; ++mi) {
            float4 b4 = *(const float4*)&bias[g * CG + ob + mi * 16 + quad * 4];
            const int o  = ob + mi * 16 + quad * 4;       // + r
            const int h  = g * HPG + (o >> 6);
            const int d0 = o & 63;
            const size_t nh = (size_t)n * HH + h;
            #pragma unroll
            for (int ni = 0; ni < 4; ++ni) {
                const int p = p0 + ni * 16 + l15;
                float y0 = acc[mi][ni][0] + b4.x;
                float y1 = acc[mi][ni][1] + b4.y;
                float y2 = acc[mi][ni][2] + b4.z;
                float y3 = acc[mi][ni][3] + b4.w;
                if (mat < 2) {
                    shortx4 pk = { f2bf(y0), f2bf(y1), f2bf(y2), f2bf(y3) };
                    *(shortx4*)&Y[(nh * WW + p) * DD + d0] = pk;   // [w][d], 8B store
                } else {
                    const size_t vb = (nh * DD + d0) * WW + p;     // [d][w]
                    Y[vb]          = f2bf(y0);
                    Y[vb + WW]     = f2bf(y1);
                    Y[vb + 2 * WW] = f2bf(y2);
                    Y[vb + 3 * WW] = f2bf(y3);
                }
            }
        }
    }
}

// ---------------------------------------------------------------------------
// Attention: bf16 MFMA flash-style, fixed-shift softmax (mask-additive, scores
// O(10) -> exp(s-SHIFT) is overflow-safe; shift cancels in O/l).
// No barriers in K-loop; P via wave-private LDS strip; l deferred to epilogue.
// grid (W/64, H, N), block 256.
// ---------------------------------------------------------------------------
#define PST 72
#define OST 68

__global__ __launch_bounds__(256) void attn(
    const short* __restrict__ Qb, const short* __restrict__ Kb,
    const short* __restrict__ Vb, const float* __restrict__ mask,
    float* __restrict__ out)
{
    __shared__ __align__(16) short Pl[4 * 16 * PST];
    __shared__ __align__(16) float Ol[DD * OST];

    const int q0   = blockIdx.x * 64;
    const int h    = blockIdx.y;
    const int n    = blockIdx.z;
    const int tid  = threadIdx.x;
    const int wid  = __builtin_amdgcn_readfirstlane(tid >> 6);
    const int lane = tid & 63;
    const int l15  = lane & 15;
    const int quad = lane >> 4;

    const size_t nh = (size_t)n * HH + h;
    const short* Kbase = Kb + nh * WW * DD;   // [key][d]
    const short* Vbase = Vb + nh * DD * WW;   // [d][w]
    const float* mbase = mask + (size_t)n * WW;

    shortx8 qf[2];
    {
        const short* qp = Qb + (nh * WW + q0 + wid * 16 + l15) * DD + quad * 8;
        qf[0] = *(const shortx8*)(qp);
        qf[1] = *(const shortx8*)(qp + 32);
    }

    floatx4 oacc[4];
    #pragma unroll
    for (int nn2 = 0; nn2 < 4; ++nn2) oacc[nn2] = (floatx4)0.0f;
    float lst[4] = {0.f, 0.f, 0.f, 0.f};

    short* Pw = Pl + wid * 16 * PST;

    for (int kt = 0; kt < WW / 64; ++kt) {
        const int k0 = kt * 64;

        shortx8 kf[4][2], vf[4][2];
        #pragma unroll
        for (int jj = 0; jj < 4; ++jj) {
            const short* kp = Kbase + (size_t)(k0 + 16 * jj + l15) * DD + quad * 8;
            kf[jj][0] = *(const shortx8*)kp;
            kf[jj][1] = *(const shortx8*)(kp + 32);
        }
        #pragma unroll
        for (int nn2 = 0; nn2 < 4; ++nn2) {
            const short* vp = Vbase + (size_t)(nn2 * 16 + l15) * WW + k0 + quad * 8;
            vf[nn2][0] = *(const shortx8*)vp;
            vf[nn2][1] = *(const shortx8*)(vp + 32);
        }
        float mvs[4];
        #pragma unroll
        for (int jj = 0; jj < 4; ++jj) mvs[jj] = mbase[k0 + 16 * jj + l15] - SHIFT;

        // S = Q K^T
        floatx4 sacc[4];
        #pragma unroll
        for (int jj = 0; jj < 4; ++jj) {
            sacc[jj] = (floatx4)0.0f;
            sacc[jj] = __builtin_amdgcn_mfma_f32_16x16x32_bf16(qf[0], kf[jj][0], sacc[jj], 0, 0, 0);
            sacc[jj] = __builtin_amdgcn_mfma_f32_16x16x32_bf16(qf[1], kf[jj][1], sacc[jj], 0, 0, 0);
        }

        // P = exp(S/8 + mask - SHIFT); accumulate per-lane l partials
        #pragma unroll
        for (int jj = 0; jj < 4; ++jj) {
            #pragma unroll
            for (int r = 0; r < 4; ++r) {
                float p = __expf(fmaf(sacc[jj][r], 0.125f, mvs[jj]));
                lst[r] += p;
                Pw[(quad * 4 + r) * PST + 16 * jj + l15] = f2bf(p);
            }
        }

        shortx8 pf0 = *(const shortx8*)&Pw[l15 * PST + quad * 8];
        shortx8 pf1 = *(const shortx8*)&Pw[l15 * PST + 32 + quad * 8];

        // O += P V
        #pragma unroll
        for (int nn2 = 0; nn2 < 4; ++nn2) {
            oacc[nn2] = __builtin_amdgcn_mfma_f32_16x16x32_bf16(pf0, vf[nn2][0], oacc[nn2], 0, 0, 0);
            oacc[nn2] = __builtin_amdgcn_mfma_f32_16x16x32_bf16(pf1, vf[nn2][1], oacc[nn2], 0, 0, 0);
        }
    }

    // epilogue: row sums (one reduction total), normalize, transpose, store
    float linv[4];
    #pragma unroll
    for (int r = 0; r < 4; ++r) linv[r] = 1.0f / rsum16(lst[r]);
    #pragma unroll
    for (int nn2 = 0; nn2 < 4; ++nn2)
        #pragma unroll
        for (int r = 0; r < 4; ++r)
            Ol[(nn2 * 16 + l15) * OST + wid * 16 + quad * 4 + r] = oacc[nn2][r] * linv[r];
    __syncthreads();
    float* obase = out + (nh * DD) * WW + q0;
    #pragma unroll
    for (int i = 0; i < 4; ++i) {
        int idx = tid * 4 + i * 1024;
        int d = idx >> 6, qq = idx & 63;
        *(floatx4*)&obase[(size_t)d * WW + qq] = *(const floatx4*)&Ol[d * OST + qq];
    }
}

// ---------------------------------------------------------------------------
extern "C" void kernel_launch(void* const* d_in, const int* in_sizes, int n_in,
                              void* d_out, int out_size, void* d_ws, size_t ws_size,
                              hipStream_t stream) {
    const float* x    = (const float*)d_in[0];
    const float* mask = (const float*)d_in[1];
    const float* wq   = (const float*)d_in[2];
    const float* bq   = (const float*)d_in[3];
    const float* wk   = (const float*)d_in[4];
    const float* bk   = (const float*)d_in[5];
    const float* wv   = (const float*)d_in[6];
    const float* bv   = (const float*)d_in[7];
    float* out = (float*)d_out;

    const size_t per = (size_t)NB * HH * WW * DD;   // 6,291,456
    short* Qb  = (short*)d_ws;
    short* Kb  = Qb + per;
    short* Vb  = Kb + per;
    short* XTh = Vb + per;
    short* XTl = XTh + per;
    short* Whp = XTl + per;
    short* Wlp = Whp + 3 * WSZ;

    hipLaunchKernelGGL(prep_x, dim3(WW / 64, CC / 64, NB), dim3(256), 0, stream,
                       x, XTh, XTl);
    hipLaunchKernelGGL(prep_w, dim3((WSZ + 255) / 256), dim3(256), 0, stream,
                       wq, wk, wv, Whp, Wlp);
    hipLaunchKernelGGL(qkv_gemm, dim3(WW / 64, GG, NB), dim3(256), 0, stream,
                       XTh, XTl, Whp, Wlp, bq, bk, bv, Qb, Kb, Vb);
    hipLaunchKernelGGL(attn, dim3(WW / 64, HH, NB), dim3(256), 0, stream,
                       Qb, Kb, Vb, mask, out);
}